// Round 22
// baseline (187.742 us; speedup 1.0000x reference)
//
#include <hip/hip_runtime.h>
#include <cstddef>
#include <cstdint>

#define CAP 64      // per-node LDS bucket capacity (Poisson(16): tail ~1e-19)
#define SCAP 40     // per-(chunk,partition) segment capacity
#define CHUNK2 4096 // edges per binscatter block
#define PR 5632     // dense bucket ints per partition (two 2816 halves)
#define HPR 2816

typedef _Float16 h2 __attribute__((ext_vector_type(2)));
typedef _Float16 f16x8 __attribute__((ext_vector_type(8)));
typedef float f32x4 __attribute__((ext_vector_type(4)));

static __device__ __forceinline__ h2 h2max(h2 a, h2 b) {
  return __builtin_elementwise_max(a, b);  // v_pk_max_f16
}
static __device__ __forceinline__ h2 bch2(int u) { return __builtin_bit_cast(h2, u); }
static __device__ __forceinline__ float fdot2f(h2 a, h2 b, float c) {
#if __has_builtin(__builtin_amdgcn_fdot2)
  return __builtin_amdgcn_fdot2(a, b, c, false);
#else
  return c + (float)a.x * (float)b.x + (float)a.y * (float)b.y;
#endif
}

// ---- MFMA helpers: XOR-swizzled row-major f16 tiles, 128B row stride ----
static __device__ __forceinline__ f16x8 fragLd(const char* base, int row, int k0) {
  return *(const f16x8*)(base + ((row * 128 + k0 * 2) ^ ((row & 7) << 4)));
}
static __device__ __forceinline__ void stageWT(char* dstLds,
                                               const float* __restrict__ W,
                                               int tid) {
  #pragma unroll
  for (int it = 0; it < 4; it++) {
    int idx = it * 256 + tid;
    int k = idx >> 4;
    int c4 = idx & 15;
    float4 wv = ((const float4*)(W + k * 64))[c4];
    #pragma unroll
    for (int j = 0; j < 4; j++) {
      int col = c4 * 4 + j;
      float val = (j == 0) ? wv.x : (j == 1) ? wv.y : (j == 2) ? wv.z : wv.w;
      *(_Float16*)(dstLds + ((col * 128 + k * 2) ^ ((col & 7) << 4))) =
          (_Float16)val;
    }
  }
}

// ---- stage 1: standalone binscatter ----
__global__ __launch_bounds__(256) void k_binscatter(const int* __restrict__ src,
                                                    const int* __restrict__ dst,
                                                    unsigned int* __restrict__ pairs,
                                                    int* __restrict__ cnt2,
                                                    int E, int P) {
  __shared__ int hcnt[512];
  int tid = threadIdx.x;
  for (int p = tid; p < 512; p += 256) hcnt[p] = 0;
  __syncthreads();
  int chunk = blockIdx.x;
  int e0 = chunk * CHUNK2;
  unsigned int* pbase = pairs + (size_t)chunk * P * SCAP;
  #pragma unroll
  for (int k = 0; k < CHUNK2 / 256; k++) {
    int e = e0 + k * 256 + tid;
    if (e < E) {
      int d = dst[e], s = src[e];
      int p = d >> 8;
      int slot = atomicAdd(&hcnt[p], 1);
      if (slot < SCAP)
        pbase[p * SCAP + slot] = (unsigned)s | ((unsigned)(d & 255) << 17);
    }
  }
  __syncthreads();
  int* cbase = cnt2 + (size_t)chunk * P;
  for (int p = tid; p < P; p += 256) {
    int c = hcnt[p];
    cbase[p] = (c < SCAP) ? c : SCAP;
  }
}

// ---- stage 2 MERGED: fill3 (blocks [0,2P)) || MFMA z1 (blocks [2P,..)) ----
__global__ __launch_bounds__(256) void k_fill3z(const unsigned int* __restrict__ pairs,
                                                const int* __restrict__ cnt2,
                                                int* __restrict__ rowcnt,
                                                int* __restrict__ bucket,
                                                int n, int NC, int P,
                                                const float* __restrict__ X,
                                                const float* __restrict__ W,
                                                const float* __restrict__ bias,
                                                _Float16* __restrict__ Z) {
  __shared__ __attribute__((aligned(16))) char smem[36864];
  int tid = threadIdx.x;
  if ((int)blockIdx.x < 2 * P) {
    int* sbucket = (int*)smem;
    int* scnt    = (int*)(smem + 32768);
    int* soff    = (int*)(smem + 33280);
    int* scnt2   = (int*)(smem + 34304);
    int p = blockIdx.x >> 1;
    int half = blockIdx.x & 1;
    if (tid < 128) scnt[tid] = 0;
    for (int c = tid; c < NC; c += 256) scnt2[c] = cnt2[(size_t)c * P + p];
    __syncthreads();
    int total = NC * SCAP;
    for (int t = tid; t < total; t += 256) {
      int chunk = t / SCAP;
      int slot = t - chunk * SCAP;
      if (slot < scnt2[chunk]) {
        unsigned int u = pairs[(size_t)chunk * P * SCAP + p * SCAP + slot];
        int dlow = (int)(u >> 17);
        if ((dlow >> 7) == half) {
          int s = (int)(u & 0x1FFFFu);
          int li = dlow & 127;
          int sl = atomicAdd(&scnt[li], 1);
          if (sl < CAP)
            sbucket[li * CAP + sl] = s;
        }
      }
    }
    __syncthreads();
    int c = 0;
    if (tid < 128) {
      c = scnt[tid];
      if (c > CAP) c = CAP;
    }
    int ca = (c + 3) & ~3;
    soff[tid] = (tid < 128) ? ca : 0;
    __syncthreads();
    #pragma unroll
    for (int off = 1; off < 256; off <<= 1) {
      int t = (tid >= off) ? soff[tid - off] : 0;
      __syncthreads();
      soff[tid] += t;
      __syncthreads();
    }
    if (tid < 128) {
      int local = soff[tid] - ca;
      int node = (p << 8) + (half << 7) + tid;
      int gbase = p * PR + half * HPR + local;
      if (node < n)
        rowcnt[node] = gbase | (c << 22);
      for (int j = 0; j < c; j += 4) {
        int4 v = *(const int4*)&sbucket[tid * CAP + j];
        *(int4*)&bucket[gbase + j] = v;
      }
    }
    return;
  }
  // ---------- z1 = relu(X @ W + b) -> fp16 rows (MFMA) ----------
  char* sX  = smem;
  char* sWT = smem + 16384;
  stageWT(sWT, W, tid);
  int node0 = ((int)blockIdx.x - 2 * P) * 128;
  #pragma unroll
  for (int it = 0; it < 8; it++) {
    int idx = it * 256 + tid;
    int row = idx & 127, c4 = idx >> 7;
    int node = node0 + row;
    float4 v = make_float4(0.f, 0.f, 0.f, 0.f);
    if (node < n) v = ((const float4*)(X + (size_t)node * 64))[c4];
    h2 lo; lo.x = (_Float16)v.x; lo.y = (_Float16)v.y;
    h2 hi; hi.x = (_Float16)v.z; hi.y = (_Float16)v.w;
    int2 pk = make_int2(__builtin_bit_cast(int, lo), __builtin_bit_cast(int, hi));
    *(int2*)(sX + ((row * 128 + c4 * 8) ^ ((row & 7) << 4))) = pk;
  }
  __syncthreads();
  int l = tid & 63;
  int wv_ = tid >> 6;
  int wrow = wv_ * 32;
  int colq = l & 15;
  int kgrp = (l >> 4) * 8;
  f32x4 acc[2][4];
  #pragma unroll
  for (int m = 0; m < 2; m++)
    #pragma unroll
    for (int nt = 0; nt < 4; nt++) {
      float bv = bias[nt * 16 + colq];
      acc[m][nt] = (f32x4){bv, bv, bv, bv};
    }
  #pragma unroll
  for (int ks = 0; ks < 64; ks += 32) {
    f16x8 xa0 = fragLd(sX, wrow + colq, ks + kgrp);
    f16x8 xa1 = fragLd(sX, wrow + 16 + colq, ks + kgrp);
    #pragma unroll
    for (int nt = 0; nt < 4; nt++) {
      f16x8 b = fragLd(sWT, nt * 16 + colq, ks + kgrp);
      acc[0][nt] = __builtin_amdgcn_mfma_f32_16x16x32_f16(xa0, b, acc[0][nt], 0, 0, 0);
      acc[1][nt] = __builtin_amdgcn_mfma_f32_16x16x32_f16(xa1, b, acc[1][nt], 0, 0, 0);
    }
  }
  __syncthreads();
  int rbase = (l >> 4) * 4;
  #pragma unroll
  for (int m = 0; m < 2; m++)
    #pragma unroll
    for (int nt = 0; nt < 4; nt++)
      #pragma unroll
      for (int r = 0; r < 4; r++) {
        int nl = wrow + m * 16 + rbase + r;
        int col = nt * 16 + colq;
        float zv = fmaxf(acc[m][nt][r], 0.f);
        *(_Float16*)(sX + ((nl * 128 + col * 2) ^ ((nl & 7) << 4))) = (_Float16)zv;
      }
  __syncthreads();
  #pragma unroll
  for (int it = 0; it < 4; it++) {
    int idx = it * 256 + tid;
    int row = idx & 127, q = idx >> 7;
    int node = node0 + row;
    if (node < n) {
      int4 u = *(const int4*)(sX + ((row * 128 + q * 16) ^ ((row & 7) << 4)));
      ((int4*)((char*)Z + (size_t)node * 128))[q] = u;
    }
  }
}

// ---- gather tail (exact remainder from j to c) ----
static __device__ __forceinline__ h2 gather_tail(const char* zb,
                                                 const int* __restrict__ bk,
                                                 int j, int c, h2 acc) {
  for (; j + 8 <= c; j += 8) {
    int4 a = *(const int4*)(bk + j);
    int4 d = *(const int4*)(bk + j + 4);
    int u0 = *(const int*)(zb + (size_t)a.x * 128);
    int u1 = *(const int*)(zb + (size_t)a.y * 128);
    int u2 = *(const int*)(zb + (size_t)a.z * 128);
    int u3 = *(const int*)(zb + (size_t)a.w * 128);
    int u4 = *(const int*)(zb + (size_t)d.x * 128);
    int u5 = *(const int*)(zb + (size_t)d.y * 128);
    int u6 = *(const int*)(zb + (size_t)d.z * 128);
    int u7 = *(const int*)(zb + (size_t)d.w * 128);
    h2 m0 = h2max(bch2(u0), bch2(u1));
    h2 m1 = h2max(bch2(u2), bch2(u3));
    h2 m2 = h2max(bch2(u4), bch2(u5));
    h2 m3 = h2max(bch2(u6), bch2(u7));
    acc = h2max(acc, h2max(h2max(m0, m1), h2max(m2, m3)));
  }
  if (j + 4 <= c) {
    int4 a = *(const int4*)(bk + j);
    int u0 = *(const int*)(zb + (size_t)a.x * 128);
    int u1 = *(const int*)(zb + (size_t)a.y * 128);
    int u2 = *(const int*)(zb + (size_t)a.z * 128);
    int u3 = *(const int*)(zb + (size_t)a.w * 128);
    acc = h2max(acc, h2max(h2max(bch2(u0), bch2(u1)), h2max(bch2(u2), bch2(u3))));
    j += 4;
  }
  if (j + 2 <= c) {
    int2 a = *(const int2*)(bk + j);
    int u0 = *(const int*)(zb + (size_t)a.x * 128);
    int u1 = *(const int*)(zb + (size_t)a.y * 128);
    acc = h2max(acc, h2max(bch2(u0), bch2(u1)));
    j += 2;
  }
  if (j < c) {
    int u0 = *(const int*)(zb + (size_t)bk[j] * 128);
    acc = h2max(acc, bch2(u0));
  }
  return acc;
}
static __device__ __forceinline__ h2 gather_one(const char* zb,
                                                const int* __restrict__ bucket,
                                                int rc) {
  return gather_tail(zb, bucket + (rc & 0x3FFFFF), 0, rc >> 22, (h2)(_Float16)0);
}

// ---- FOUR nodes, chains interleaved: 32 z-loads in flight per lane ----
static __device__ __forceinline__ void gather_four(const char* zb,
                                                   const int* __restrict__ bucket,
                                                   int4 rc, h2* out) {
  int c0 = rc.x >> 22, c1 = rc.y >> 22, c2 = rc.z >> 22, c3 = rc.w >> 22;
  const int* b0 = bucket + (rc.x & 0x3FFFFF);
  const int* b1 = bucket + (rc.y & 0x3FFFFF);
  const int* b2 = bucket + (rc.z & 0x3FFFFF);
  const int* b3 = bucket + (rc.w & 0x3FFFFF);
  h2 z = (h2)(_Float16)0;
  h2 a0 = z, a1 = z, a2 = z, a3 = z;
  int cm = min(min(c0, c1), min(c2, c3));
  int j = 0;
  for (; j + 8 <= cm; j += 8) {
    int4 xa = *(const int4*)(b0 + j); int4 ya = *(const int4*)(b0 + j + 4);
    int4 xb = *(const int4*)(b1 + j); int4 yb = *(const int4*)(b1 + j + 4);
    int4 xc = *(const int4*)(b2 + j); int4 yc = *(const int4*)(b2 + j + 4);
    int4 xd = *(const int4*)(b3 + j); int4 yd = *(const int4*)(b3 + j + 4);
    int A0 = *(const int*)(zb + (size_t)xa.x * 128);
    int A1 = *(const int*)(zb + (size_t)xa.y * 128);
    int A2 = *(const int*)(zb + (size_t)xa.z * 128);
    int A3 = *(const int*)(zb + (size_t)xa.w * 128);
    int A4 = *(const int*)(zb + (size_t)ya.x * 128);
    int A5 = *(const int*)(zb + (size_t)ya.y * 128);
    int A6 = *(const int*)(zb + (size_t)ya.z * 128);
    int A7 = *(const int*)(zb + (size_t)ya.w * 128);
    int B0 = *(const int*)(zb + (size_t)xb.x * 128);
    int B1 = *(const int*)(zb + (size_t)xb.y * 128);
    int B2 = *(const int*)(zb + (size_t)xb.z * 128);
    int B3 = *(const int*)(zb + (size_t)xb.w * 128);
    int B4 = *(const int*)(zb + (size_t)yb.x * 128);
    int B5 = *(const int*)(zb + (size_t)yb.y * 128);
    int B6 = *(const int*)(zb + (size_t)yb.z * 128);
    int B7 = *(const int*)(zb + (size_t)yb.w * 128);
    int C0 = *(const int*)(zb + (size_t)xc.x * 128);
    int C1 = *(const int*)(zb + (size_t)xc.y * 128);
    int C2 = *(const int*)(zb + (size_t)xc.z * 128);
    int C3 = *(const int*)(zb + (size_t)xc.w * 128);
    int C4 = *(const int*)(zb + (size_t)yc.x * 128);
    int C5 = *(const int*)(zb + (size_t)yc.y * 128);
    int C6 = *(const int*)(zb + (size_t)yc.z * 128);
    int C7 = *(const int*)(zb + (size_t)yc.w * 128);
    int D0 = *(const int*)(zb + (size_t)xd.x * 128);
    int D1 = *(const int*)(zb + (size_t)xd.y * 128);
    int D2 = *(const int*)(zb + (size_t)xd.z * 128);
    int D3 = *(const int*)(zb + (size_t)xd.w * 128);
    int D4 = *(const int*)(zb + (size_t)yd.x * 128);
    int D5 = *(const int*)(zb + (size_t)yd.y * 128);
    int D6 = *(const int*)(zb + (size_t)yd.z * 128);
    int D7 = *(const int*)(zb + (size_t)yd.w * 128);
    a0 = h2max(a0, h2max(h2max(h2max(bch2(A0), bch2(A1)), h2max(bch2(A2), bch2(A3))),
                         h2max(h2max(bch2(A4), bch2(A5)), h2max(bch2(A6), bch2(A7)))));
    a1 = h2max(a1, h2max(h2max(h2max(bch2(B0), bch2(B1)), h2max(bch2(B2), bch2(B3))),
                         h2max(h2max(bch2(B4), bch2(B5)), h2max(bch2(B6), bch2(B7)))));
    a2 = h2max(a2, h2max(h2max(h2max(bch2(C0), bch2(C1)), h2max(bch2(C2), bch2(C3))),
                         h2max(h2max(bch2(C4), bch2(C5)), h2max(bch2(C6), bch2(C7)))));
    a3 = h2max(a3, h2max(h2max(h2max(bch2(D0), bch2(D1)), h2max(bch2(D2), bch2(D3))),
                         h2max(h2max(bch2(D4), bch2(D5)), h2max(bch2(D6), bch2(D7)))));
  }
  out[0] = gather_tail(zb, b0, j, c0, a0);
  out[1] = gather_tail(zb, b1, j, c1, a1);
  out[2] = gather_tail(zb, b2, j, c2, a2);
  out[3] = gather_tail(zb, b3, j, c3, a3);
}

// ---- gather-1: half-wave handles FOUR nodes ----
__global__ __launch_bounds__(256) void k_gather2(const _Float16* __restrict__ Z,
                                                 const int* __restrict__ bucket,
                                                 const int* __restrict__ rowcnt,
                                                 _Float16* __restrict__ pooled, int n) {
  int t = blockIdx.x * 256 + threadIdx.x;
  int quad = t >> 5;
  int sub = t & 31;
  int nA = quad * 4;
  if (nA >= n) return;
  const char* zb = (const char*)Z + sub * 4;
  if (nA + 3 < n) {
    int4 rc = *(const int4*)&rowcnt[nA];
    h2 out[4];
    gather_four(zb, bucket, rc, out);
    #pragma unroll
    for (int q = 0; q < 4; q++)
      *(int*)((char*)pooled + (size_t)(nA + q) * 128 + sub * 4) =
          __builtin_bit_cast(int, out[q]);
  } else {
    for (int q = 0; nA + q < n && q < 4; q++) {
      h2 a = gather_one(zb, bucket, rowcnt[nA + q]);
      *(int*)((char*)pooled + (size_t)(nA + q) * 128 + sub * 4) =
          __builtin_bit_cast(int, a);
    }
  }
}

// ---- MFMA FUSED: H(fp16) = leaky(X@Ws + P@Wn + b); Z2 = relu(H@Wp2+bp2) ----
__global__ __launch_bounds__(256) void k_hl(const float* __restrict__ X,
                                            const _Float16* __restrict__ P,
                                            const float* __restrict__ Ws,
                                            const float* __restrict__ Wn,
                                            const float* __restrict__ bias,
                                            const float* __restrict__ Wp2,
                                            const float* __restrict__ bp2,
                                            _Float16* __restrict__ H,
                                            _Float16* __restrict__ Z2, int n) {
  __shared__ __attribute__((aligned(16))) char sX[128 * 128];
  __shared__ __attribute__((aligned(16))) char sP[128 * 128];
  __shared__ __attribute__((aligned(16))) char sWsT[64 * 128];
  __shared__ __attribute__((aligned(16))) char sWnT[64 * 128];
  int tid = threadIdx.x;
  stageWT(sWsT, Ws, tid);
  stageWT(sWnT, Wn, tid);
  int node0 = blockIdx.x * 128;
  #pragma unroll
  for (int it = 0; it < 8; it++) {
    int idx = it * 256 + tid;
    int row = idx & 127, c4 = idx >> 7;
    int node = node0 + row;
    float4 v = make_float4(0.f, 0.f, 0.f, 0.f);
    if (node < n) v = ((const float4*)(X + (size_t)node * 64))[c4];
    h2 lo; lo.x = (_Float16)v.x; lo.y = (_Float16)v.y;
    h2 hi; hi.x = (_Float16)v.z; hi.y = (_Float16)v.w;
    int2 pk = make_int2(__builtin_bit_cast(int, lo), __builtin_bit_cast(int, hi));
    *(int2*)(sX + ((row * 128 + c4 * 8) ^ ((row & 7) << 4))) = pk;
  }
  #pragma unroll
  for (int it = 0; it < 4; it++) {
    int idx = it * 256 + tid;
    int row = idx & 127, q = idx >> 7;
    int node = node0 + row;
    int4 u = make_int4(0, 0, 0, 0);
    if (node < n) u = ((const int4*)((const char*)P + (size_t)node * 128))[q];
    *(int4*)(sP + ((row * 128 + q * 16) ^ ((row & 7) << 4))) = u;
  }
  __syncthreads();
  int l = tid & 63;
  int wv_ = tid >> 6;
  int wrow = wv_ * 32;
  int colq = l & 15;
  int kgrp = (l >> 4) * 8;
  f32x4 acc[2][4];
  #pragma unroll
  for (int m = 0; m < 2; m++)
    #pragma unroll
    for (int nt = 0; nt < 4; nt++) {
      float bv = bias[nt * 16 + colq];
      acc[m][nt] = (f32x4){bv, bv, bv, bv};
    }
  #pragma unroll
  for (int ks = 0; ks < 64; ks += 32) {
    f16x8 xa0 = fragLd(sX, wrow + colq, ks + kgrp);
    f16x8 xa1 = fragLd(sX, wrow + 16 + colq, ks + kgrp);
    f16x8 pa0 = fragLd(sP, wrow + colq, ks + kgrp);
    f16x8 pa1 = fragLd(sP, wrow + 16 + colq, ks + kgrp);
    #pragma unroll
    for (int nt = 0; nt < 4; nt++) {
      f16x8 bs = fragLd(sWsT, nt * 16 + colq, ks + kgrp);
      f16x8 bn = fragLd(sWnT, nt * 16 + colq, ks + kgrp);
      acc[0][nt] = __builtin_amdgcn_mfma_f32_16x16x32_f16(xa0, bs, acc[0][nt], 0, 0, 0);
      acc[1][nt] = __builtin_amdgcn_mfma_f32_16x16x32_f16(xa1, bs, acc[1][nt], 0, 0, 0);
      acc[0][nt] = __builtin_amdgcn_mfma_f32_16x16x32_f16(pa0, bn, acc[0][nt], 0, 0, 0);
      acc[1][nt] = __builtin_amdgcn_mfma_f32_16x16x32_f16(pa1, bn, acc[1][nt], 0, 0, 0);
    }
  }
  __syncthreads();
  int rbase = (l >> 4) * 4;
  #pragma unroll
  for (int m = 0; m < 2; m++)
    #pragma unroll
    for (int nt = 0; nt < 4; nt++)
      #pragma unroll
      for (int r = 0; r < 4; r++) {
        int nl = wrow + m * 16 + rbase + r;
        int col = nt * 16 + colq;
        float hv = acc[m][nt][r];
        hv = (hv >= 0.f) ? hv : 0.01f * hv;
        *(_Float16*)(sX + ((nl * 128 + col * 2) ^ ((nl & 7) << 4))) = (_Float16)hv;
      }
  stageWT(sWsT, Wp2, tid);
  __syncthreads();
  #pragma unroll
  for (int it = 0; it < 4; it++) {
    int idx = it * 256 + tid;
    int row = idx & 127, q = idx >> 7;
    int node = node0 + row;
    if (node < n) {
      int4 u = *(const int4*)(sX + ((row * 128 + q * 16) ^ ((row & 7) << 4)));
      ((int4*)((char*)H + (size_t)node * 128))[q] = u;
    }
  }
  f32x4 acc2[2][4];
  #pragma unroll
  for (int m = 0; m < 2; m++)
    #pragma unroll
    for (int nt = 0; nt < 4; nt++) {
      float bv = bp2[nt * 16 + colq];
      acc2[m][nt] = (f32x4){bv, bv, bv, bv};
    }
  #pragma unroll
  for (int ks = 0; ks < 64; ks += 32) {
    f16x8 ha0 = fragLd(sX, wrow + colq, ks + kgrp);
    f16x8 ha1 = fragLd(sX, wrow + 16 + colq, ks + kgrp);
    #pragma unroll
    for (int nt = 0; nt < 4; nt++) {
      f16x8 b = fragLd(sWsT, nt * 16 + colq, ks + kgrp);
      acc2[0][nt] = __builtin_amdgcn_mfma_f32_16x16x32_f16(ha0, b, acc2[0][nt], 0, 0, 0);
      acc2[1][nt] = __builtin_amdgcn_mfma_f32_16x16x32_f16(ha1, b, acc2[1][nt], 0, 0, 0);
    }
  }
  #pragma unroll
  for (int m = 0; m < 2; m++)
    #pragma unroll
    for (int nt = 0; nt < 4; nt++)
      #pragma unroll
      for (int r = 0; r < 4; r++) {
        int nl = wrow + m * 16 + rbase + r;
        int col = nt * 16 + colq;
        float zv = fmaxf(acc2[m][nt][r], 0.f);
        *(_Float16*)(sP + ((nl * 128 + col * 2) ^ ((nl & 7) << 4))) = (_Float16)zv;
      }
  __syncthreads();
  #pragma unroll
  for (int it = 0; it < 4; it++) {
    int idx = it * 256 + tid;
    int row = idx & 127, q = idx >> 7;
    int node = node0 + row;
    if (node < n) {
      int4 u = *(const int4*)(sP + ((row * 128 + q * 16) ^ ((row & 7) << 4)));
      ((int4*)((char*)Z2 + (size_t)node * 128))[q] = u;
    }
  }
}

// ---- FUSED gather-2 + OUT: 32 nodes/block, 4 nodes per half-wave ----
__global__ __launch_bounds__(256) void k_gather_out(const _Float16* __restrict__ Z,
                                                    const int* __restrict__ bucket,
                                                    const int* __restrict__ rowcnt,
                                                    const _Float16* __restrict__ Hrow,
                                                    const float* __restrict__ Ws,
                                                    const float* __restrict__ Wn,
                                                    const float* __restrict__ bias,
                                                    float* __restrict__ OUT, int n) {
  __shared__ __attribute__((aligned(16))) h2 sWs[32 * 16];
  __shared__ __attribute__((aligned(16))) h2 sWn[32 * 16];
  __shared__ __attribute__((aligned(16))) h2 sH[32][32];
  __shared__ __attribute__((aligned(16))) h2 sP[32][32];
  __shared__ float sB[16];
  int tid = threadIdx.x;
  #pragma unroll
  for (int it = 0; it < 2; it++) {
    int idx = it * 256 + tid;
    int kp = idx >> 4, c = idx & 15;
    h2 t1, t2;
    t1.x = (_Float16)Ws[(2 * kp) * 16 + c];
    t1.y = (_Float16)Ws[(2 * kp + 1) * 16 + c];
    t2.x = (_Float16)Wn[(2 * kp) * 16 + c];
    t2.y = (_Float16)Wn[(2 * kp + 1) * 16 + c];
    sWs[kp * 16 + c] = t1;
    sWn[kp * 16 + c] = t2;
  }
  if (tid < 16) sB[tid] = bias[tid];
  int nodeBase = blockIdx.x * 32;
  {
    int nd = nodeBase + (tid >> 3);
    int q = tid & 7;
    int4 u = make_int4(0, 0, 0, 0);
    if (nd < n) u = ((const int4*)((const char*)Hrow + (size_t)nd * 128))[q];
    ((int4*)&sH[tid >> 3][0])[q] = u;
  }
  int en = tid >> 5;        // half-wave id 0..7
  int sub = tid & 31;
  int nA = nodeBase + 4 * en;
  const char* zb = (const char*)Z + sub * 4;
  h2 out[4];
  out[0] = out[1] = out[2] = out[3] = (h2)(_Float16)0;
  if (nA + 3 < n) {
    int4 rc = *(const int4*)&rowcnt[nA];
    gather_four(zb, bucket, rc, out);
  } else {
    for (int q = 0; nA + q < n && q < 4; q++)
      out[q] = gather_one(zb, bucket, rowcnt[nA + q]);
  }
  #pragma unroll
  for (int q = 0; q < 4; q++) sP[4 * en + q][sub] = out[q];
  __syncthreads();
  // epilogue: 2 passes of (node e, col); 32 nodes x 16 cols = 512 slots
  int col = tid & 15;
  #pragma unroll
  for (int pass = 0; pass < 2; pass++) {
    int e = (tid >> 4) + pass * 16;
    int node = nodeBase + e;
    float v = 0.f;
    #pragma unroll
    for (int kp = 0; kp < 32; kp++) {
      v = fdot2f(sH[e][kp], sWs[kp * 16 + col], v);
      v = fdot2f(sP[e][kp], sWn[kp * 16 + col], v);
    }
    if (node < n)
      OUT[(size_t)node * 16 + col] = v + sB[col];
  }
}

extern "C" void kernel_launch(void* const* d_in, const int* in_sizes, int n_in,
                              void* d_out, int out_size, void* d_ws, size_t ws_size,
                              hipStream_t stream) {
  const float* X   = (const float*)d_in[0];
  const int*   src = (const int*)d_in[1];
  const int*   dst = (const int*)d_in[2];
  const float* Wp1 = (const float*)d_in[3];
  const float* bp1 = (const float*)d_in[4];
  const float* Ws1 = (const float*)d_in[5];
  const float* Wn1 = (const float*)d_in[6];
  const float* b1  = (const float*)d_in[7];
  const float* Wp2 = (const float*)d_in[8];
  const float* bp2 = (const float*)d_in[9];
  const float* Ws2 = (const float*)d_in[10];
  const float* Wn2 = (const float*)d_in[11];
  const float* b2  = (const float*)d_in[12];
  float* OUT = (float*)d_out;

  const int n = in_sizes[0] / 64;
  const int E = in_sizes[1];
  const int P = (n + 255) >> 8;                 // dst partitions (391)
  const int NC = (E + CHUNK2 - 1) / CHUNK2;     // binscatter chunks (391)

  char* w = (char*)d_ws;
  auto alloc = [&](size_t bytes) -> char* {
    char* p = w;
    w += (bytes + 255) & ~(size_t)255;
    return p;
  };
  int*  rowcnt = (int*)alloc((size_t)n * 4);
  int*  bucket = (int*)alloc((size_t)P * PR * 4);   // dense CSR (~8.8MB)
  int*  cnt2   = (int*)alloc((size_t)NC * P * 4);
  size_t pairs_b = (size_t)NC * P * SCAP * 4;
  size_t h_b     = (size_t)n * 64 * 2;
  char* ali = alloc(pairs_b > h_b ? pairs_b : h_b);
  unsigned int* pairs = (unsigned int*)ali;
  _Float16*     h16   = (_Float16*)ali;
  _Float16* zh     = (_Float16*)alloc((size_t)n * 64 * 2);
  _Float16* pooled = (_Float16*)alloc((size_t)n * 64 * 2);
  (void)ws_size; (void)n_in; (void)out_size;

  const int nbT   = (n + 127) / 128;
  const int nbG4  = (n * 8 + 255) / 256;     // 4-node-per-half-wave gather grid
  const int nbG32 = (n + 31) / 32;           // fused gather+out grid

  k_binscatter<<<NC, 256, 0, stream>>>(src, dst, pairs, cnt2, E, P);
  k_fill3z<<<2 * P + nbT, 256, 0, stream>>>(pairs, cnt2, rowcnt, bucket,
                                            n, NC, P, X, Wp1, bp1, zh);
  k_gather2<<<nbG4, 256, 0, stream>>>(zh, bucket, rowcnt, pooled, n);
  k_hl<<<nbT, 256, 0, stream>>>(X, pooled, Ws1, Wn1, b1, Wp2, bp2, h16, zh, n);
  k_gather_out<<<nbG32, 256, 0, stream>>>(zh, bucket, rowcnt, h16,
                                          Ws2, Wn2, b2, OUT, n);
}

// Round 23
// 156.780 us; speedup vs baseline: 1.1975x; 1.1975x over previous
//
#include <hip/hip_runtime.h>
#include <cstddef>
#include <cstdint>

#define CAP 64      // per-node LDS bucket capacity (Poisson(16): tail ~1e-19)
#define SCAP 40     // per-(chunk,partition) segment capacity
#define CHUNK2 4096 // edges per binscatter block
#define PR 5632     // dense bucket ints per partition (two 2816 halves)
#define HPR 2816

typedef _Float16 h2 __attribute__((ext_vector_type(2)));
typedef _Float16 f16x8 __attribute__((ext_vector_type(8)));
typedef float f32x4 __attribute__((ext_vector_type(4)));

static __device__ __forceinline__ h2 h2max(h2 a, h2 b) {
  return __builtin_elementwise_max(a, b);  // v_pk_max_f16
}
static __device__ __forceinline__ h2 bch2(int u) { return __builtin_bit_cast(h2, u); }
static __device__ __forceinline__ float fdot2f(h2 a, h2 b, float c) {
#if __has_builtin(__builtin_amdgcn_fdot2)
  return __builtin_amdgcn_fdot2(a, b, c, false);
#else
  return c + (float)a.x * (float)b.x + (float)a.y * (float)b.y;
#endif
}

// ---- MFMA helpers: XOR-swizzled row-major f16 tiles, 128B row stride ----
static __device__ __forceinline__ f16x8 fragLd(const char* base, int row, int k0) {
  return *(const f16x8*)(base + ((row * 128 + k0 * 2) ^ ((row & 7) << 4)));
}
static __device__ __forceinline__ void stageWT(char* dstLds,
                                               const float* __restrict__ W,
                                               int tid) {
  #pragma unroll
  for (int it = 0; it < 4; it++) {
    int idx = it * 256 + tid;
    int k = idx >> 4;
    int c4 = idx & 15;
    float4 wv = ((const float4*)(W + k * 64))[c4];
    #pragma unroll
    for (int j = 0; j < 4; j++) {
      int col = c4 * 4 + j;
      float val = (j == 0) ? wv.x : (j == 1) ? wv.y : (j == 2) ? wv.z : wv.w;
      *(_Float16*)(dstLds + ((col * 128 + k * 2) ^ ((col & 7) << 4))) =
          (_Float16)val;
    }
  }
}

// ---- stage 1: standalone binscatter ----
__global__ __launch_bounds__(256) void k_binscatter(const int* __restrict__ src,
                                                    const int* __restrict__ dst,
                                                    unsigned int* __restrict__ pairs,
                                                    int* __restrict__ cnt2,
                                                    int E, int P) {
  __shared__ int hcnt[512];
  int tid = threadIdx.x;
  for (int p = tid; p < 512; p += 256) hcnt[p] = 0;
  __syncthreads();
  int chunk = blockIdx.x;
  int e0 = chunk * CHUNK2;
  unsigned int* pbase = pairs + (size_t)chunk * P * SCAP;
  #pragma unroll
  for (int k = 0; k < CHUNK2 / 256; k++) {
    int e = e0 + k * 256 + tid;
    if (e < E) {
      int d = dst[e], s = src[e];
      int p = d >> 8;
      int slot = atomicAdd(&hcnt[p], 1);
      if (slot < SCAP)
        pbase[p * SCAP + slot] = (unsigned)s | ((unsigned)(d & 255) << 17);
    }
  }
  __syncthreads();
  int* cbase = cnt2 + (size_t)chunk * P;
  for (int p = tid; p < P; p += 256) {
    int c = hcnt[p];
    cbase[p] = (c < SCAP) ? c : SCAP;
  }
}

// ---- stage 2 MERGED: fill3 (blocks [0,2P)) || MFMA z1 (blocks [2P,..)) ----
__global__ __launch_bounds__(256) void k_fill3z(const unsigned int* __restrict__ pairs,
                                                const int* __restrict__ cnt2,
                                                int* __restrict__ rowcnt,
                                                int* __restrict__ bucket,
                                                int n, int NC, int P,
                                                const float* __restrict__ X,
                                                const float* __restrict__ W,
                                                const float* __restrict__ bias,
                                                _Float16* __restrict__ Z) {
  __shared__ __attribute__((aligned(16))) char smem[36864];
  int tid = threadIdx.x;
  if ((int)blockIdx.x < 2 * P) {
    int* sbucket = (int*)smem;
    int* scnt    = (int*)(smem + 32768);
    int* soff    = (int*)(smem + 33280);
    int* scnt2   = (int*)(smem + 34304);
    int p = blockIdx.x >> 1;
    int half = blockIdx.x & 1;
    if (tid < 128) scnt[tid] = 0;
    for (int c = tid; c < NC; c += 256) scnt2[c] = cnt2[(size_t)c * P + p];
    __syncthreads();
    int total = NC * SCAP;
    for (int t = tid; t < total; t += 256) {
      int chunk = t / SCAP;
      int slot = t - chunk * SCAP;
      if (slot < scnt2[chunk]) {
        unsigned int u = pairs[(size_t)chunk * P * SCAP + p * SCAP + slot];
        int dlow = (int)(u >> 17);
        if ((dlow >> 7) == half) {
          int s = (int)(u & 0x1FFFFu);
          int li = dlow & 127;
          int sl = atomicAdd(&scnt[li], 1);
          if (sl < CAP)
            sbucket[li * CAP + sl] = s;
        }
      }
    }
    __syncthreads();
    int c = 0;
    if (tid < 128) {
      c = scnt[tid];
      if (c > CAP) c = CAP;
    }
    int ca = (c + 3) & ~3;
    soff[tid] = (tid < 128) ? ca : 0;
    __syncthreads();
    #pragma unroll
    for (int off = 1; off < 256; off <<= 1) {
      int t = (tid >= off) ? soff[tid - off] : 0;
      __syncthreads();
      soff[tid] += t;
      __syncthreads();
    }
    if (tid < 128) {
      int local = soff[tid] - ca;
      int node = (p << 8) + (half << 7) + tid;
      int gbase = p * PR + half * HPR + local;
      if (node < n)
        rowcnt[node] = gbase | (c << 22);
      for (int j = 0; j < c; j += 4) {
        int4 v = *(const int4*)&sbucket[tid * CAP + j];
        *(int4*)&bucket[gbase + j] = v;
      }
    }
    return;
  }
  // ---------- z1 = relu(X @ W + b) -> fp16 rows (MFMA) ----------
  char* sX  = smem;
  char* sWT = smem + 16384;
  stageWT(sWT, W, tid);
  int node0 = ((int)blockIdx.x - 2 * P) * 128;
  #pragma unroll
  for (int it = 0; it < 8; it++) {
    int idx = it * 256 + tid;
    int row = idx & 127, c4 = idx >> 7;
    int node = node0 + row;
    float4 v = make_float4(0.f, 0.f, 0.f, 0.f);
    if (node < n) v = ((const float4*)(X + (size_t)node * 64))[c4];
    h2 lo; lo.x = (_Float16)v.x; lo.y = (_Float16)v.y;
    h2 hi; hi.x = (_Float16)v.z; hi.y = (_Float16)v.w;
    int2 pk = make_int2(__builtin_bit_cast(int, lo), __builtin_bit_cast(int, hi));
    *(int2*)(sX + ((row * 128 + c4 * 8) ^ ((row & 7) << 4))) = pk;
  }
  __syncthreads();
  int l = tid & 63;
  int wv_ = tid >> 6;
  int wrow = wv_ * 32;
  int colq = l & 15;
  int kgrp = (l >> 4) * 8;
  f32x4 acc[2][4];
  #pragma unroll
  for (int m = 0; m < 2; m++)
    #pragma unroll
    for (int nt = 0; nt < 4; nt++) {
      float bv = bias[nt * 16 + colq];
      acc[m][nt] = (f32x4){bv, bv, bv, bv};
    }
  #pragma unroll
  for (int ks = 0; ks < 64; ks += 32) {
    f16x8 xa0 = fragLd(sX, wrow + colq, ks + kgrp);
    f16x8 xa1 = fragLd(sX, wrow + 16 + colq, ks + kgrp);
    #pragma unroll
    for (int nt = 0; nt < 4; nt++) {
      f16x8 b = fragLd(sWT, nt * 16 + colq, ks + kgrp);
      acc[0][nt] = __builtin_amdgcn_mfma_f32_16x16x32_f16(xa0, b, acc[0][nt], 0, 0, 0);
      acc[1][nt] = __builtin_amdgcn_mfma_f32_16x16x32_f16(xa1, b, acc[1][nt], 0, 0, 0);
    }
  }
  __syncthreads();
  int rbase = (l >> 4) * 4;
  #pragma unroll
  for (int m = 0; m < 2; m++)
    #pragma unroll
    for (int nt = 0; nt < 4; nt++)
      #pragma unroll
      for (int r = 0; r < 4; r++) {
        int nl = wrow + m * 16 + rbase + r;
        int col = nt * 16 + colq;
        float zv = fmaxf(acc[m][nt][r], 0.f);
        *(_Float16*)(sX + ((nl * 128 + col * 2) ^ ((nl & 7) << 4))) = (_Float16)zv;
      }
  __syncthreads();
  #pragma unroll
  for (int it = 0; it < 4; it++) {
    int idx = it * 256 + tid;
    int row = idx & 127, q = idx >> 7;
    int node = node0 + row;
    if (node < n) {
      int4 u = *(const int4*)(sX + ((row * 128 + q * 16) ^ ((row & 7) << 4)));
      ((int4*)((char*)Z + (size_t)node * 128))[q] = u;
    }
  }
}

// ---- gather tail (exact remainder from j to c) ----
static __device__ __forceinline__ h2 gather_tail(const char* zb,
                                                 const int* __restrict__ bk,
                                                 int j, int c, h2 acc) {
  for (; j + 8 <= c; j += 8) {
    int4 a = *(const int4*)(bk + j);
    int4 d = *(const int4*)(bk + j + 4);
    int u0 = *(const int*)(zb + (size_t)a.x * 128);
    int u1 = *(const int*)(zb + (size_t)a.y * 128);
    int u2 = *(const int*)(zb + (size_t)a.z * 128);
    int u3 = *(const int*)(zb + (size_t)a.w * 128);
    int u4 = *(const int*)(zb + (size_t)d.x * 128);
    int u5 = *(const int*)(zb + (size_t)d.y * 128);
    int u6 = *(const int*)(zb + (size_t)d.z * 128);
    int u7 = *(const int*)(zb + (size_t)d.w * 128);
    h2 m0 = h2max(bch2(u0), bch2(u1));
    h2 m1 = h2max(bch2(u2), bch2(u3));
    h2 m2 = h2max(bch2(u4), bch2(u5));
    h2 m3 = h2max(bch2(u6), bch2(u7));
    acc = h2max(acc, h2max(h2max(m0, m1), h2max(m2, m3)));
  }
  if (j + 4 <= c) {
    int4 a = *(const int4*)(bk + j);
    int u0 = *(const int*)(zb + (size_t)a.x * 128);
    int u1 = *(const int*)(zb + (size_t)a.y * 128);
    int u2 = *(const int*)(zb + (size_t)a.z * 128);
    int u3 = *(const int*)(zb + (size_t)a.w * 128);
    acc = h2max(acc, h2max(h2max(bch2(u0), bch2(u1)), h2max(bch2(u2), bch2(u3))));
    j += 4;
  }
  if (j + 2 <= c) {
    int2 a = *(const int2*)(bk + j);
    int u0 = *(const int*)(zb + (size_t)a.x * 128);
    int u1 = *(const int*)(zb + (size_t)a.y * 128);
    acc = h2max(acc, h2max(bch2(u0), bch2(u1)));
    j += 2;
  }
  if (j < c) {
    int u0 = *(const int*)(zb + (size_t)bk[j] * 128);
    acc = h2max(acc, bch2(u0));
  }
  return acc;
}
static __device__ __forceinline__ h2 gather_one(const char* zb,
                                                const int* __restrict__ bucket,
                                                int rc) {
  return gather_tail(zb, bucket + (rc & 0x3FFFFF), 0, rc >> 22, (h2)(_Float16)0);
}

// ---- TWO nodes, chains truly interleaved (16 z-loads in flight) ----
static __device__ __forceinline__ void gather_two(const char* zb,
                                                  const int* __restrict__ bucket,
                                                  int rcA, int rcB,
                                                  h2* outA, h2* outB) {
  int cA = rcA >> 22, cB = rcB >> 22;
  const int* bA = bucket + (rcA & 0x3FFFFF);
  const int* bB = bucket + (rcB & 0x3FFFFF);
  h2 aA = (h2)(_Float16)0, aB = (h2)(_Float16)0;
  int cm = (cA < cB) ? cA : cB;
  int j = 0;
  for (; j + 8 <= cm; j += 8) {  // fused main loop: 16 independent z-loads
    int4 xa = *(const int4*)(bA + j);
    int4 ya = *(const int4*)(bA + j + 4);
    int4 xb = *(const int4*)(bB + j);
    int4 yb = *(const int4*)(bB + j + 4);
    int a0 = *(const int*)(zb + (size_t)xa.x * 128);
    int a1 = *(const int*)(zb + (size_t)xa.y * 128);
    int a2 = *(const int*)(zb + (size_t)xa.z * 128);
    int a3 = *(const int*)(zb + (size_t)xa.w * 128);
    int a4 = *(const int*)(zb + (size_t)ya.x * 128);
    int a5 = *(const int*)(zb + (size_t)ya.y * 128);
    int a6 = *(const int*)(zb + (size_t)ya.z * 128);
    int a7 = *(const int*)(zb + (size_t)ya.w * 128);
    int b0 = *(const int*)(zb + (size_t)xb.x * 128);
    int b1 = *(const int*)(zb + (size_t)xb.y * 128);
    int b2 = *(const int*)(zb + (size_t)xb.z * 128);
    int b3 = *(const int*)(zb + (size_t)xb.w * 128);
    int b4 = *(const int*)(zb + (size_t)yb.x * 128);
    int b5 = *(const int*)(zb + (size_t)yb.y * 128);
    int b6 = *(const int*)(zb + (size_t)yb.z * 128);
    int b7 = *(const int*)(zb + (size_t)yb.w * 128);
    h2 mA0 = h2max(bch2(a0), bch2(a1));
    h2 mA1 = h2max(bch2(a2), bch2(a3));
    h2 mA2 = h2max(bch2(a4), bch2(a5));
    h2 mA3 = h2max(bch2(a6), bch2(a7));
    aA = h2max(aA, h2max(h2max(mA0, mA1), h2max(mA2, mA3)));
    h2 mB0 = h2max(bch2(b0), bch2(b1));
    h2 mB1 = h2max(bch2(b2), bch2(b3));
    h2 mB2 = h2max(bch2(b4), bch2(b5));
    h2 mB3 = h2max(bch2(b6), bch2(b7));
    aB = h2max(aB, h2max(h2max(mB0, mB1), h2max(mB2, mB3)));
  }
  *outA = gather_tail(zb, bA, j, cA, aA);
  *outB = gather_tail(zb, bB, j, cB, aB);
}

// ---- gather-1: half-wave handles TWO nodes (fused chains) ----
__global__ __launch_bounds__(256) void k_gather2(const _Float16* __restrict__ Z,
                                                 const int* __restrict__ bucket,
                                                 const int* __restrict__ rowcnt,
                                                 _Float16* __restrict__ pooled, int n) {
  int t = blockIdx.x * 256 + threadIdx.x;
  int pairid = t >> 5;
  int sub = t & 31;
  int nA = pairid * 2;
  int nB = nA + 1;
  if (nA >= n) return;
  const char* zb = (const char*)Z + sub * 4;
  if (nB < n) {
    h2 accA, accB;
    gather_two(zb, bucket, rowcnt[nA], rowcnt[nB], &accA, &accB);
    *(int*)((char*)pooled + (size_t)nA * 128 + sub * 4) = __builtin_bit_cast(int, accA);
    *(int*)((char*)pooled + (size_t)nB * 128 + sub * 4) = __builtin_bit_cast(int, accB);
  } else {
    h2 accA = gather_one(zb, bucket, rowcnt[nA]);
    *(int*)((char*)pooled + (size_t)nA * 128 + sub * 4) = __builtin_bit_cast(int, accA);
  }
}

// ---- MFMA FUSED: H(fp16) = leaky(X@Ws + P@Wn + b); Z2 = relu(H@Wp2+bp2) ----
__global__ __launch_bounds__(256) void k_hl(const float* __restrict__ X,
                                            const _Float16* __restrict__ P,
                                            const float* __restrict__ Ws,
                                            const float* __restrict__ Wn,
                                            const float* __restrict__ bias,
                                            const float* __restrict__ Wp2,
                                            const float* __restrict__ bp2,
                                            _Float16* __restrict__ H,
                                            _Float16* __restrict__ Z2, int n) {
  __shared__ __attribute__((aligned(16))) char sX[128 * 128];
  __shared__ __attribute__((aligned(16))) char sP[128 * 128];
  __shared__ __attribute__((aligned(16))) char sWsT[64 * 128];
  __shared__ __attribute__((aligned(16))) char sWnT[64 * 128];
  int tid = threadIdx.x;
  stageWT(sWsT, Ws, tid);
  stageWT(sWnT, Wn, tid);
  int node0 = blockIdx.x * 128;
  #pragma unroll
  for (int it = 0; it < 8; it++) {
    int idx = it * 256 + tid;
    int row = idx & 127, c4 = idx >> 7;
    int node = node0 + row;
    float4 v = make_float4(0.f, 0.f, 0.f, 0.f);
    if (node < n) v = ((const float4*)(X + (size_t)node * 64))[c4];
    h2 lo; lo.x = (_Float16)v.x; lo.y = (_Float16)v.y;
    h2 hi; hi.x = (_Float16)v.z; hi.y = (_Float16)v.w;
    int2 pk = make_int2(__builtin_bit_cast(int, lo), __builtin_bit_cast(int, hi));
    *(int2*)(sX + ((row * 128 + c4 * 8) ^ ((row & 7) << 4))) = pk;
  }
  #pragma unroll
  for (int it = 0; it < 4; it++) {
    int idx = it * 256 + tid;
    int row = idx & 127, q = idx >> 7;
    int node = node0 + row;
    int4 u = make_int4(0, 0, 0, 0);
    if (node < n) u = ((const int4*)((const char*)P + (size_t)node * 128))[q];
    *(int4*)(sP + ((row * 128 + q * 16) ^ ((row & 7) << 4))) = u;
  }
  __syncthreads();
  int l = tid & 63;
  int wv_ = tid >> 6;
  int wrow = wv_ * 32;
  int colq = l & 15;
  int kgrp = (l >> 4) * 8;
  f32x4 acc[2][4];
  #pragma unroll
  for (int m = 0; m < 2; m++)
    #pragma unroll
    for (int nt = 0; nt < 4; nt++) {
      float bv = bias[nt * 16 + colq];
      acc[m][nt] = (f32x4){bv, bv, bv, bv};
    }
  #pragma unroll
  for (int ks = 0; ks < 64; ks += 32) {
    f16x8 xa0 = fragLd(sX, wrow + colq, ks + kgrp);
    f16x8 xa1 = fragLd(sX, wrow + 16 + colq, ks + kgrp);
    f16x8 pa0 = fragLd(sP, wrow + colq, ks + kgrp);
    f16x8 pa1 = fragLd(sP, wrow + 16 + colq, ks + kgrp);
    #pragma unroll
    for (int nt = 0; nt < 4; nt++) {
      f16x8 bs = fragLd(sWsT, nt * 16 + colq, ks + kgrp);
      f16x8 bn = fragLd(sWnT, nt * 16 + colq, ks + kgrp);
      acc[0][nt] = __builtin_amdgcn_mfma_f32_16x16x32_f16(xa0, bs, acc[0][nt], 0, 0, 0);
      acc[1][nt] = __builtin_amdgcn_mfma_f32_16x16x32_f16(xa1, bs, acc[1][nt], 0, 0, 0);
      acc[0][nt] = __builtin_amdgcn_mfma_f32_16x16x32_f16(pa0, bn, acc[0][nt], 0, 0, 0);
      acc[1][nt] = __builtin_amdgcn_mfma_f32_16x16x32_f16(pa1, bn, acc[1][nt], 0, 0, 0);
    }
  }
  __syncthreads();
  int rbase = (l >> 4) * 4;
  #pragma unroll
  for (int m = 0; m < 2; m++)
    #pragma unroll
    for (int nt = 0; nt < 4; nt++)
      #pragma unroll
      for (int r = 0; r < 4; r++) {
        int nl = wrow + m * 16 + rbase + r;
        int col = nt * 16 + colq;
        float hv = acc[m][nt][r];
        hv = (hv >= 0.f) ? hv : 0.01f * hv;
        *(_Float16*)(sX + ((nl * 128 + col * 2) ^ ((nl & 7) << 4))) = (_Float16)hv;
      }
  stageWT(sWsT, Wp2, tid);
  __syncthreads();
  #pragma unroll
  for (int it = 0; it < 4; it++) {
    int idx = it * 256 + tid;
    int row = idx & 127, q = idx >> 7;
    int node = node0 + row;
    if (node < n) {
      int4 u = *(const int4*)(sX + ((row * 128 + q * 16) ^ ((row & 7) << 4)));
      ((int4*)((char*)H + (size_t)node * 128))[q] = u;
    }
  }
  f32x4 acc2[2][4];
  #pragma unroll
  for (int m = 0; m < 2; m++)
    #pragma unroll
    for (int nt = 0; nt < 4; nt++) {
      float bv = bp2[nt * 16 + colq];
      acc2[m][nt] = (f32x4){bv, bv, bv, bv};
    }
  #pragma unroll
  for (int ks = 0; ks < 64; ks += 32) {
    f16x8 ha0 = fragLd(sX, wrow + colq, ks + kgrp);
    f16x8 ha1 = fragLd(sX, wrow + 16 + colq, ks + kgrp);
    #pragma unroll
    for (int nt = 0; nt < 4; nt++) {
      f16x8 b = fragLd(sWsT, nt * 16 + colq, ks + kgrp);
      acc2[0][nt] = __builtin_amdgcn_mfma_f32_16x16x32_f16(ha0, b, acc2[0][nt], 0, 0, 0);
      acc2[1][nt] = __builtin_amdgcn_mfma_f32_16x16x32_f16(ha1, b, acc2[1][nt], 0, 0, 0);
    }
  }
  #pragma unroll
  for (int m = 0; m < 2; m++)
    #pragma unroll
    for (int nt = 0; nt < 4; nt++)
      #pragma unroll
      for (int r = 0; r < 4; r++) {
        int nl = wrow + m * 16 + rbase + r;
        int col = nt * 16 + colq;
        float zv = fmaxf(acc2[m][nt][r], 0.f);
        *(_Float16*)(sP + ((nl * 128 + col * 2) ^ ((nl & 7) << 4))) = (_Float16)zv;
      }
  __syncthreads();
  #pragma unroll
  for (int it = 0; it < 4; it++) {
    int idx = it * 256 + tid;
    int row = idx & 127, q = idx >> 7;
    int node = node0 + row;
    if (node < n) {
      int4 u = *(const int4*)(sP + ((row * 128 + q * 16) ^ ((row & 7) << 4)));
      ((int4*)((char*)Z2 + (size_t)node * 128))[q] = u;
    }
  }
}

// ---- FUSED gather-2 + OUT: 16 nodes/block, 2 nodes per half-wave ----
__global__ __launch_bounds__(256) void k_gather_out(const _Float16* __restrict__ Z,
                                                    const int* __restrict__ bucket,
                                                    const int* __restrict__ rowcnt,
                                                    const _Float16* __restrict__ Hrow,
                                                    const float* __restrict__ Ws,
                                                    const float* __restrict__ Wn,
                                                    const float* __restrict__ bias,
                                                    float* __restrict__ OUT, int n) {
  __shared__ __attribute__((aligned(16))) h2 sWs[32 * 16];
  __shared__ __attribute__((aligned(16))) h2 sWn[32 * 16];
  __shared__ __attribute__((aligned(16))) h2 sH[16][32];
  __shared__ __attribute__((aligned(16))) h2 sP[16][32];
  __shared__ float sB[16];
  int tid = threadIdx.x;
  #pragma unroll
  for (int it = 0; it < 2; it++) {
    int idx = it * 256 + tid;
    int kp = idx >> 4, c = idx & 15;
    h2 t1, t2;
    t1.x = (_Float16)Ws[(2 * kp) * 16 + c];
    t1.y = (_Float16)Ws[(2 * kp + 1) * 16 + c];
    t2.x = (_Float16)Wn[(2 * kp) * 16 + c];
    t2.y = (_Float16)Wn[(2 * kp + 1) * 16 + c];
    sWs[kp * 16 + c] = t1;
    sWn[kp * 16 + c] = t2;
  }
  if (tid < 16) sB[tid] = bias[tid];
  int nodeBase = blockIdx.x * 16;
  if (tid < 128) {
    int nd = nodeBase + (tid >> 3);
    int q = tid & 7;
    int4 u = make_int4(0, 0, 0, 0);
    if (nd < n) u = ((const int4*)((const char*)Hrow + (size_t)nd * 128))[q];
    ((int4*)&sH[tid >> 3][0])[q] = u;
  }
  int en = tid >> 5;        // half-wave id 0..7
  int sub = tid & 31;
  int nA = nodeBase + 2 * en;
  int nB = nA + 1;
  const char* zb = (const char*)Z + sub * 4;
  h2 accA = (h2)(_Float16)0, accB = (h2)(_Float16)0;
  if (nB < n) {
    gather_two(zb, bucket, rowcnt[nA], rowcnt[nB], &accA, &accB);
  } else if (nA < n) {
    accA = gather_one(zb, bucket, rowcnt[nA]);
  }
  sP[2 * en][sub] = accA;
  sP[2 * en + 1][sub] = accB;
  __syncthreads();
  // epilogue: thread = (node e 0..15, col 0..15), full 32-kp loop
  int e = tid >> 4;
  int col = tid & 15;
  int node = nodeBase + e;
  float v = 0.f;
  #pragma unroll
  for (int kp = 0; kp < 32; kp++) {
    v = fdot2f(sH[e][kp], sWs[kp * 16 + col], v);
    v = fdot2f(sP[e][kp], sWn[kp * 16 + col], v);
  }
  if (node < n)
    OUT[(size_t)node * 16 + col] = v + sB[col];
}

extern "C" void kernel_launch(void* const* d_in, const int* in_sizes, int n_in,
                              void* d_out, int out_size, void* d_ws, size_t ws_size,
                              hipStream_t stream) {
  const float* X   = (const float*)d_in[0];
  const int*   src = (const int*)d_in[1];
  const int*   dst = (const int*)d_in[2];
  const float* Wp1 = (const float*)d_in[3];
  const float* bp1 = (const float*)d_in[4];
  const float* Ws1 = (const float*)d_in[5];
  const float* Wn1 = (const float*)d_in[6];
  const float* b1  = (const float*)d_in[7];
  const float* Wp2 = (const float*)d_in[8];
  const float* bp2 = (const float*)d_in[9];
  const float* Ws2 = (const float*)d_in[10];
  const float* Wn2 = (const float*)d_in[11];
  const float* b2  = (const float*)d_in[12];
  float* OUT = (float*)d_out;

  const int n = in_sizes[0] / 64;
  const int E = in_sizes[1];
  const int P = (n + 255) >> 8;                 // dst partitions (391)
  const int NC = (E + CHUNK2 - 1) / CHUNK2;     // binscatter chunks (391)

  char* w = (char*)d_ws;
  auto alloc = [&](size_t bytes) -> char* {
    char* p = w;
    w += (bytes + 255) & ~(size_t)255;
    return p;
  };
  int*  rowcnt = (int*)alloc((size_t)n * 4);
  int*  bucket = (int*)alloc((size_t)P * PR * 4);   // dense CSR (~8.8MB)
  int*  cnt2   = (int*)alloc((size_t)NC * P * 4);
  size_t pairs_b = (size_t)NC * P * SCAP * 4;
  size_t h_b     = (size_t)n * 64 * 2;
  char* ali = alloc(pairs_b > h_b ? pairs_b : h_b);
  unsigned int* pairs = (unsigned int*)ali;
  _Float16*     h16   = (_Float16*)ali;
  _Float16* zh     = (_Float16*)alloc((size_t)n * 64 * 2);
  _Float16* pooled = (_Float16*)alloc((size_t)n * 64 * 2);
  (void)ws_size; (void)n_in; (void)out_size;

  const int nbT   = (n + 127) / 128;
  const int nbG2  = (n * 16 + 255) / 256;
  const int nbG16 = (n + 15) / 16;

  k_binscatter<<<NC, 256, 0, stream>>>(src, dst, pairs, cnt2, E, P);
  k_fill3z<<<2 * P + nbT, 256, 0, stream>>>(pairs, cnt2, rowcnt, bucket,
                                            n, NC, P, X, Wp1, bp1, zh);
  k_gather2<<<nbG2, 256, 0, stream>>>(zh, bucket, rowcnt, pooled, n);
  k_hl<<<nbT, 256, 0, stream>>>(X, pooled, Ws1, Wn1, b1, Wp2, bp2, h16, zh, n);
  k_gather_out<<<nbG16, 256, 0, stream>>>(zh, bucket, rowcnt, h16,
                                          Ws2, Wn2, b2, OUT, n);
}